// Round 5
// baseline (454.629 us; speedup 1.0000x reference)
//
#include <hip/hip_runtime.h>
#include <math.h>

#define FLAT   8192
#define NB     64
#define OD_    80
#define NE_    512
#define EATT_  4096
#define MAXACT 4096
// part2: 400 floats/node of contraction partials (plain stores, no atomics):
//   [0..255]   8 group-slices x 32 out_s slots   (groups 0..7  = cc 0..23)
//   [256..303] 3 group-slices x 16 q slots       (groups 8..10 = cc 24..31)
//   [304..399] 2 group-slices x 48 D slots       (groups 10..11= cc 32..35)
#define PARTW2 400

typedef __bf16 v8bf __attribute__((ext_vector_type(8)));
typedef float  v4f  __attribute__((ext_vector_type(4)));

__device__ __forceinline__ float silu_f(float x) { return x / (1.f + __expf(-x)); }
__device__ __forceinline__ float sigm_f(float x) { return 1.f / (1.f + __expf(-x)); }

// ================= k_prep: init + gabs + scales + coalesced weight transposes =================
// blocks 0..35  : w2_rad -> w2rt hi/lo [n][k]
// block  36     : wo2 -> w2t hi/lo
// blocks 37..38 : wo3 -> w3t hi/lo
// blocks 39..70 : gabs (2 batches per block)
// blocks 71..102: init (widx=-1, vabs=0, count=0)
// blocks 103..358: scales (2 rows per block)
__device__ __forceinline__ void transpose_split(const float* __restrict__ src, int ld,
                                                int nbase, __bf16* wh, __bf16* wl,
                                                float (*lds)[129]) {
  int t = threadIdx.x;  // 256
#pragma unroll
  for (int it = 0; it < 16; ++it) {
    int idx = it * 256 + t;
    int r = idx >> 5, c4 = idx & 31;
    float4 v = *(const float4*)(src + (size_t)r * ld + nbase + c4 * 4);
    lds[r][c4 * 4 + 0] = v.x;
    lds[r][c4 * 4 + 1] = v.y;
    lds[r][c4 * 4 + 2] = v.z;
    lds[r][c4 * 4 + 3] = v.w;
  }
  __syncthreads();
  int n = t >> 1, kh = (t & 1) * 64;
  union { __bf16 b[64]; uint4 u[8]; } H, L;
#pragma unroll
  for (int k = 0; k < 64; ++k) {
    float v = lds[kh + k][n];
    __bf16 hv = (__bf16)v;
    H.b[k] = hv;
    L.b[k] = (__bf16)(v - (float)hv);
  }
  uint4* ph = (uint4*)(wh + (size_t)(nbase + n) * 128 + kh);
  uint4* pl = (uint4*)(wl + (size_t)(nbase + n) * 128 + kh);
#pragma unroll
  for (int i = 0; i < 8; ++i) { ph[i] = H.u[i]; pl[i] = L.u[i]; }
}

__global__ __launch_bounds__(256) void k_prep(
    const float* __restrict__ w2_rad, const float* __restrict__ wo2,
    const float* __restrict__ wo3,
    const int* __restrict__ abs_idx, const float* __restrict__ h,
    const float* __restrict__ wg1,
    const float* __restrict__ e_feat,
    const float* __restrict__ we1, const float* __restrict__ be1,
    const float* __restrict__ we2, const float* __restrict__ be2,
    __bf16* w2rt_h, __bf16* w2rt_l, __bf16* w2t_h, __bf16* w2t_l,
    __bf16* w3t_h, __bf16* w3t_l,
    float* habs_g, float* vabs, int* widx, int* count, float* sfull) {
  __shared__ float lds[128][129];
  int bid = blockIdx.x;
  int t = threadIdx.x;
  if (bid < 36) {
    transpose_split(w2_rad, 4608, bid * 128, w2rt_h, w2rt_l, lds);
  } else if (bid < 37) {
    transpose_split(wo2, 128, 0, w2t_h, w2t_l, lds);
  } else if (bid < 39) {
    transpose_split(wo3, 256, (bid - 37) * 128, w3t_h, w3t_l, lds);
  } else if (bid < 71) {
    float* hs = &lds[0][0];  // [2][128]
    int half = t >> 7, tt = t & 127;
    int b = (bid - 39) * 2 + half;
    int nabs = abs_idx[b];
    hs[half * 128 + tt] = h[(size_t)(b * 128 + nabs) * 128 + tt];
    __syncthreads();
    float g = 0.f;
    for (int c = 0; c < 128; ++c) g = fmaf(hs[half * 128 + c], wg1[c * 128 + tt], g);
    habs_g[b * 128 + tt] = g;
  } else if (bid < 103) {
    int g = (bid - 71) * 256 + t;
    if (g < FLAT) widx[g] = -1;
    if (g < NB * OD_) vabs[g] = 0.f;
    if (g == 0) *count = 0;
  } else {
    // scales: 2 rows per block
    float* hid = &lds[0][0];  // [2][128]
    int half = t >> 7, tt = t & 127;
    int row = (bid - 103) * 2 + half;
    const float* ef = e_feat + row * 16;
    float s = be1[tt];
    for (int k = 0; k < 16; ++k) s = fmaf(ef[k], we1[k * 128 + tt], s);
    hid[half * 128 + tt] = silu_f(s);
    __syncthreads();
    if (tt < 48) {
      float o = be2[tt];
      for (int k = 0; k < 128; ++k) o = fmaf(hid[half * 128 + k], we2[k * 48 + tt], o);
      if (tt < 32) sfull[row * 80 + tt] = o;
      else {
        int oo = tt - 32;
        sfull[row * 80 + 32 + oo * 3 + 0] = o;
        sfull[row * 80 + 32 + oo * 3 + 1] = o;
        sfull[row * 80 + 32 + oo * 3 + 2] = o;
      }
    }
  }
}

// ---------------- scatter: last-write-wins == max edge index ----------------
__global__ void k_scatter(const int* __restrict__ att_dst, int* widx) {
  int i = blockIdx.x * 256 + threadIdx.x;
  if (i < EATT_) atomicMax(&widx[att_dst[i]], i);
}

// ---------------- compact active-node list ----------------
__global__ void k_build(const int* __restrict__ widx, int* active, int* count) {
  int j = blockIdx.x * 256 + threadIdx.x;
  if (j < FLAT && widx[j] >= 0) {
    int p = atomicAdd(count, 1);
    active[p] = j;
  }
}

// ======== k_node4: 4 nodes per block; shared wg1/w1_rad column loads ========
__global__ __launch_bounds__(128) void k_node4(
    const int* __restrict__ count, const int* __restrict__ active,
    const int* __restrict__ widx,
    const float* __restrict__ att_dist, const float* __restrict__ att_vec,
    const int* __restrict__ z, const float* __restrict__ w_zemb,
    const int* __restrict__ abs_idx,
    const float* __restrict__ w1_rad, const float* __restrict__ b1_rad,
    const float* __restrict__ h, const float* __restrict__ habs_g,
    const float* __restrict__ wg1, const float* __restrict__ bg1,
    const float* __restrict__ wg2, const float* __restrict__ bg2,
    const float* __restrict__ h_full,
    __bf16* ah_glob, __bf16* al_glob,
    float* coef_glob, float* meta_f, int* meta_b) {
  int cnt = *count;
  int pbase = blockIdx.x * 4;
  if (pbase >= cnt) return;
  int t = threadIdx.x;  // 128

  __shared__ float win[4][49];
  __shared__ float yv_s[4][3];
  __shared__ float sh_d[4];
  __shared__ float red[4][128];
  __shared__ float hsh[4][128];

  bool ok[4];
  int jj[4], ee[4], bb[4];
  float isab[4];
#pragma unroll
  for (int q = 0; q < 4; ++q) {
    int pos = pbase + q;
    ok[q] = pos < cnt;
    jj[q] = ok[q] ? active[pos] : 0;
    ee[q] = ok[q] ? widx[jj[q]] : 0;
    if (ee[q] < 0) ee[q] = 0;
    bb[q] = jj[q] >> 7;
    isab[q] = ((jj[q] & 127) == abs_idx[bb[q]]) ? 1.f : 0.f;
  }

  if (t < 4) {
    int q = t;
    float d = att_dist[ee[q]];
    sh_d[q] = d;
    float eps = fmaxf(d, 1e-8f);
    const float s3 = 1.7320508075688772f;
    yv_s[q][0] = s3 * att_vec[ee[q] * 3 + 0] / eps;
    yv_s[q][1] = s3 * att_vec[ee[q] * 3 + 1] / eps;
    yv_s[q][2] = s3 * att_vec[ee[q] * 3 + 2] / eps;
  }
#pragma unroll
  for (int q = 0; q < 4; ++q) {
    if (t < 32) win[q][t] = w_zemb[z[jj[q]] * 32 + t];
    if (t == 32) win[q][32] = isab[q];
    if (t >= 33 && t < 49) {
      int k = t - 33;
      float d = att_dist[ee[q]];
      float x = (d - (float)k * (1.f / 3.f)) * 3.f;  // width = 1/3
      win[q][t] = __expf(-0.5f * x * x);
    }
    hsh[q][t] = h[(size_t)jj[q] * 128 + t];
  }
  __syncthreads();

  // hidden a = silu(win @ w1_rad + b1) per node, w1_rad column loaded once
  {
    float s[4];
    float bv = b1_rad[t];
#pragma unroll
    for (int q = 0; q < 4; ++q) s[q] = bv;
    for (int k = 0; k < 49; ++k) {
      float wv = w1_rad[k * 128 + t];
#pragma unroll
      for (int q = 0; q < 4; ++q) s[q] = fmaf(win[q][k], wv, s[q]);
    }
#pragma unroll
    for (int q = 0; q < 4; ++q) {
      if (ok[q]) {
        float av = silu_f(s[q]);
        __bf16 hv = (__bf16)av;
        ah_glob[(size_t)(pbase + q) * 128 + t] = hv;
        al_glob[(size_t)(pbase + q) * 128 + t] = (__bf16)(av - (float)hv);
      }
    }
  }

  // gate MLP hidden (273 -> 128), wg1 column loaded once per c
  {
    float g[4];
#pragma unroll
    for (int q = 0; q < 4; ++q) g[q] = bg1[t] + habs_g[bb[q] * 128 + t];
    for (int c = 0; c < 128; ++c) {
      float wv = wg1[(128 + c) * 128 + t];
#pragma unroll
      for (int q = 0; q < 4; ++q) g[q] = fmaf(hsh[q][c], wv, g[q]);
    }
    for (int k = 0; k < 16; ++k) {
      float wv = wg1[(256 + k) * 128 + t];
#pragma unroll
      for (int q = 0; q < 4; ++q) g[q] = fmaf(win[q][33 + k], wv, g[q]);
    }
    {
      float wv = wg1[272 * 128 + t];
#pragma unroll
      for (int q = 0; q < 4; ++q) g[q] = fmaf(isab[q], wv, g[q]);
    }
    float w2v = wg2[t];
#pragma unroll
    for (int q = 0; q < 4; ++q) red[q][t] = silu_f(g[q]) * w2v;
  }
  __syncthreads();

  // per-node contraction coefficients: [s1(64), p*inv_s3(32), v1(96)]
#pragma unroll
  for (int q = 0; q < 4; ++q) {
    if (!ok[q]) continue;
    int pos = pbase + q;
    const float* hf = h_full + (size_t)jj[q] * 160;
    if (t < 64) coef_glob[pos * 192 + t] = hf[t];
    if (t >= 64 && t < 96) {
      int i = t - 64;
      float pv = hf[64 + i * 3 + 0] * yv_s[q][0] + hf[64 + i * 3 + 1] * yv_s[q][1] +
                 hf[64 + i * 3 + 2] * yv_s[q][2];
      coef_glob[pos * 192 + t] = pv * 0.5773502691896258f;
    }
    if (t < 96) coef_glob[pos * 192 + 96 + t] = hf[64 + t];
  }

  if (t < 4) {
    int q = t;
    if (ok[q]) {
      int pos = pbase + q;
      float tot = 0.f;
      for (int k = 0; k < 128; ++k) tot += red[q][k];
      tot += bg2[0];
      float gate = sigm_f(tot);
      float d = sh_d[q];
      float env = (d < 5.f) ? 0.5f * (__cosf(3.14159265358979323846f * d * 0.2f) + 1.f) : 0.f;
      meta_f[pos * 4 + 0] = yv_s[q][0];
      meta_f[pos * 4 + 1] = yv_s[q][1];
      meta_f[pos * 4 + 2] = yv_s[q][2];
      meta_f[pos * 4 + 3] = gate * env;
      meta_b[pos] = bb[q];
    }
  }
}

// ---------------- split-bf16 MFMA radial GEMM + register-fused contraction ----------------
// Grid (12 groups x 3 cc, 32 node-blocks of 128). A-fragments held in registers
// for the whole block (loaded once); contraction accumulated in registers over
// the group's 3 cc; part2 written with plain coalesced stores.
__global__ __launch_bounds__(256) void k_mrgemm2(
    const int* __restrict__ count,
    const __bf16* __restrict__ Ah, const __bf16* __restrict__ Al,
    const __bf16* __restrict__ Bh, const __bf16* __restrict__ Bl,
    const float* __restrict__ b2, const float* __restrict__ coef_glob,
    float* __restrict__ part2) {
  int g = blockIdx.x;             // 0..11 (cc = g*3 .. g*3+2)
  int nbase = blockIdx.y * 128;   // 32 y-blocks
  int cnt = *count;
  if (nbase >= cnt) return;
  int t = threadIdx.x;
  int w = t >> 6, l = t & 63;
  int kg = l >> 4, ln = l & 15;

  __shared__ v8bf Bs[2][2][8][64];   // [buf][plane][nt][lane] 32 KB

  // A fragments for both M-tiles, all 4 kb — loaded once
  v8bf Afh[2][4], Afl[2][4];
#pragma unroll
  for (int mi = 0; mi < 2; ++mi) {
    size_t ar = (size_t)(nbase + (2 * w + mi) * 16 + ln) * 128 + kg * 8;
#pragma unroll
    for (int kb = 0; kb < 4; ++kb) {
      Afh[mi][kb] = *(const v8bf*)(Ah + ar + kb * 32);
      Afl[mi][kb] = *(const v8bf*)(Al + ar + kb * 32);
    }
  }

  float sS0[2][4] = {}, sS1[2][4] = {}, sQ[2][4] = {};
  float sD[2][4][3] = {};

  // stage step 0
  {
    int cc0 = g * 3;
    size_t p0 = (size_t)(cc0 * 128 + w * 16 + ln) * 128 + kg * 8;
    size_t p1 = (size_t)(cc0 * 128 + (w + 4) * 16 + ln) * 128 + kg * 8;
    Bs[0][0][w][l]     = *(const v8bf*)(Bh + p0);
    Bs[0][0][w + 4][l] = *(const v8bf*)(Bh + p1);
    Bs[0][1][w][l]     = *(const v8bf*)(Bl + p0);
    Bs[0][1][w + 4][l] = *(const v8bf*)(Bl + p1);
  }
  __syncthreads();

  v4f acc[2][8];
  v4f z4 = {0.f, 0.f, 0.f, 0.f};
#pragma unroll
  for (int i = 0; i < 2; ++i)
#pragma unroll
    for (int j = 0; j < 8; ++j) acc[i][j] = z4;

  for (int s = 0; s < 12; ++s) {
    int cur = s & 1;
    int kb = s & 3, ci = s >> 2;
    v8bf r0, r1, r2, r3;
    if (s < 11) {
      int cc_n = g * 3 + ((s + 1) >> 2), kb_n = (s + 1) & 3;
      size_t p0 = (size_t)(cc_n * 128 + w * 16 + ln) * 128 + kb_n * 32 + kg * 8;
      size_t p1 = (size_t)(cc_n * 128 + (w + 4) * 16 + ln) * 128 + kb_n * 32 + kg * 8;
      r0 = *(const v8bf*)(Bh + p0);
      r1 = *(const v8bf*)(Bh + p1);
      r2 = *(const v8bf*)(Bl + p0);
      r3 = *(const v8bf*)(Bl + p1);
    }
#pragma unroll
    for (int nt = 0; nt < 8; ++nt) {
      v8bf bh = Bs[cur][0][nt][l];
      v8bf bl = Bs[cur][1][nt][l];
      acc[0][nt] = __builtin_amdgcn_mfma_f32_16x16x32_bf16(Afh[0][kb], bh, acc[0][nt], 0, 0, 0);
      acc[0][nt] = __builtin_amdgcn_mfma_f32_16x16x32_bf16(Afl[0][kb], bh, acc[0][nt], 0, 0, 0);
      acc[0][nt] = __builtin_amdgcn_mfma_f32_16x16x32_bf16(Afh[0][kb], bl, acc[0][nt], 0, 0, 0);
      acc[1][nt] = __builtin_amdgcn_mfma_f32_16x16x32_bf16(Afh[1][kb], bh, acc[1][nt], 0, 0, 0);
      acc[1][nt] = __builtin_amdgcn_mfma_f32_16x16x32_bf16(Afl[1][kb], bh, acc[1][nt], 0, 0, 0);
      acc[1][nt] = __builtin_amdgcn_mfma_f32_16x16x32_bf16(Afh[1][kb], bl, acc[1][nt], 0, 0, 0);
    }
    if (s < 11) {
      int nxt = cur ^ 1;
      Bs[nxt][0][w][l]     = r0;
      Bs[nxt][0][w + 4][l] = r1;
      Bs[nxt][1][w][l]     = r2;
      Bs[nxt][1][w + 4][l] = r3;
    }
    __syncthreads();

    if (kb == 3) {
      int cc = g * 3 + ci;
      float b2v[8];
#pragma unroll
      for (int nt = 0; nt < 8; ++nt) b2v[nt] = b2[cc * 128 + nt * 16 + ln];
#pragma unroll
      for (int mi = 0; mi < 2; ++mi) {
        int nodeb = nbase + (2 * w + mi) * 16 + kg * 4;
#pragma unroll
        for (int j = 0; j < 4; ++j) {
          int nd = nodeb + j;
          if (nd >= cnt) continue;
          const float* cf = coef_glob + (size_t)nd * 192;
          if (cc < 24) {
            float s0 = 0.f, s1 = 0.f;
#pragma unroll
            for (int m = 0; m < 4; ++m) {
              float c = cf[cc * 4 + m];
              s0 = fmaf(acc[mi][2 * m][j] + b2v[2 * m], c, s0);
              s1 = fmaf(acc[mi][2 * m + 1][j] + b2v[2 * m + 1], c, s1);
            }
            sS0[mi][j] += s0;
            sS1[mi][j] += s1;
          } else if (cc < 32) {
            float sq = 0.f;
#pragma unroll
            for (int nt = 0; nt < 8; ++nt)
              sq = fmaf(acc[mi][nt][j] + b2v[nt], cf[(cc - 24) * 8 + nt], sq);
            sQ[mi][j] += sq;
          } else {
            float s0 = 0.f, s1 = 0.f, s2 = 0.f;
#pragma unroll
            for (int nt = 0; nt < 8; ++nt) {
              float x = acc[mi][nt][j] + b2v[nt];
              const float* c3 = cf + 96 + ((cc - 32) * 8 + nt) * 3;
              s0 = fmaf(x, c3[0], s0);
              s1 = fmaf(x, c3[1], s1);
              s2 = fmaf(x, c3[2], s2);
            }
            sD[mi][j][0] += s0;
            sD[mi][j][1] += s1;
            sD[mi][j][2] += s2;
          }
        }
      }
      // reset acc for next cc
#pragma unroll
      for (int i = 0; i < 2; ++i)
#pragma unroll
        for (int j = 0; j < 8; ++j) acc[i][j] = z4;
    }
  }

  // final stores: each (node, slot, slice) owned by exactly one thread
#pragma unroll
  for (int mi = 0; mi < 2; ++mi) {
#pragma unroll
    for (int j = 0; j < 4; ++j) {
      int nd = nbase + (2 * w + mi) * 16 + kg * 4 + j;
      if (nd >= cnt) continue;
      float* pw = part2 + (size_t)nd * PARTW2;
      if (g < 8) {
        pw[g * 32 + ln]      = sS0[mi][j];
        pw[g * 32 + 16 + ln] = sS1[mi][j];
      } else if (g < 10) {
        pw[256 + (g - 8) * 16 + ln] = sQ[mi][j];
      } else if (g == 10) {
        pw[256 + 2 * 16 + ln] = sQ[mi][j];
        pw[304 + ln]      = sD[mi][j][0];
        pw[304 + 16 + ln] = sD[mi][j][1];
        pw[304 + 32 + ln] = sD[mi][j][2];
      } else {
        pw[304 + 48 + ln]      = sD[mi][j][0];
        pw[304 + 48 + 16 + ln] = sD[mi][j][1];
        pw[304 + 48 + 32 + ln] = sD[mi][j][2];
      }
    }
  }
}

// ---------------- combine part2 slices -> v_abs[b][80] ----------------
__global__ void k_combine(const int* __restrict__ count, const float* __restrict__ part2,
                          const float* __restrict__ meta_f, const int* __restrict__ meta_b,
                          float* vabs) {
  int t = threadIdx.x;
  int pos = blockIdx.x * 2 + (t >> 7);
  int slot = t & 127;
  if (pos >= *count || slot >= 96) return;
  const float* pp = part2 + (size_t)pos * PARTW2;
  float s = 0.f;
  if (slot < 32) {
#pragma unroll
    for (int c = 0; c < 8; ++c) s += pp[c * 32 + slot];
  } else if (slot < 48) {
#pragma unroll
    for (int c = 0; c < 3; ++c) s += pp[256 + c * 16 + (slot - 32)];
  } else {
#pragma unroll
    for (int c = 0; c < 2; ++c) s += pp[304 + c * 48 + (slot - 48)];
  }
  float sc = meta_f[pos * 4 + 3] * 0.10206207261596577f;  // gate*env / sqrt(96)
  float* vb = vabs + meta_b[pos] * 80;
  if (slot < 32) {
    unsafeAtomicAdd(&vb[slot], s * sc);
  } else if (slot < 48) {
    int o = slot - 32;
    float q = s * sc;
    unsafeAtomicAdd(&vb[32 + o * 3 + 0], q * meta_f[pos * 4 + 0]);
    unsafeAtomicAdd(&vb[32 + o * 3 + 1], q * meta_f[pos * 4 + 1]);
    unsafeAtomicAdd(&vb[32 + o * 3 + 2], q * meta_f[pos * 4 + 2]);
  } else {
    int s2 = slot - 48;          // comp*16 + o
    int comp = s2 >> 4, o = s2 & 15;
    unsafeAtomicAdd(&vb[32 + o * 3 + comp], s * sc);
  }
}

// ================= k_head: hg1 + head layer2 + head layer3, fused per 64 rows =================
// Phase A: inv build + (64x48)@wo1 fp32 GEMM + silu -> xs (LDS bf16 hi/lo, swizzled)
// Phase B: xs @ w2t^T (split-bf16 MFMA, K=128) + silu -> ys (LDS)
// Phase C: ys @ w3t^T (2 col-chunks of 128) + bo3 -> out
// LDS arena 68 KB, phase-aliased. Swizzle: byte ^= (row&7)<<4 (rows are 256 B).
__global__ __launch_bounds__(256) void k_head(
    const float* __restrict__ vabs, const float* __restrict__ sfull,
    const float* __restrict__ wo1, const float* __restrict__ bo1,
    const __bf16* __restrict__ W2h, const __bf16* __restrict__ W2l,
    const float* __restrict__ bo2,
    const __bf16* __restrict__ W3h, const __bf16* __restrict__ W3l,
    const float* __restrict__ bo3,
    float* __restrict__ out) {
  __shared__ __align__(16) char arena[69632];
  // region1 [0,36864): phase A {w_s 24K | invt 12K}; later xs_h/xs_l (32K); later BsC (32K)
  // region2 [36864,69632): va (0.3K, phase A); BsB (32K, phase B); ys_h/ys_l (32K, B->C)
  float* w_s = (float*)arena;
  float (*invt)[64] = (float(*)[64])(arena + 24576);
  float* va = (float*)(arena + 36864);
  char* xsh = arena;
  char* xsl = arena + 16384;
  v8bf (*BsB)[2][8][64] = (v8bf(*)[2][8][64])(arena + 36864);
  char* ysh = arena + 36864;
  char* ysl = arena + 53248;
  v8bf (*BsC)[2][8][64] = (v8bf(*)[2][8][64])arena;

  int rbase = blockIdx.x * 64;   // 512 blocks
  int b = rbase >> 9;
  int e0 = rbase & 511;
  int t = threadIdx.x;

  // ---------------- phase A (verbatim hg1 math) ----------------
  {
    int tx = t & 15, ty = t >> 4;
    int n0 = ty * 4;
    if (t < 80) va[t] = vabs[b * 80 + t];
    {
      const float4* wg = (const float4*)wo1;
      float4* ws4 = (float4*)w_s;
#pragma unroll
      for (int it = 0; it < 6; ++it) ws4[t + it * 256] = wg[t + it * 256];
    }
    __syncthreads();

    for (int idx = t; idx < 48 * 64; idx += 256) {
      int cd = idx >> 6, r = idx & 63;
      const float* sf = sfull + (size_t)(e0 + r) * 80;
      float v;
      if (cd < 32) v = va[cd] * sf[cd];
      else {
        int base = 32 + (cd - 32) * 3;
        float m0 = va[base + 0] * sf[base + 0];
        float m1 = va[base + 1] * sf[base + 1];
        float m2 = va[base + 2] * sf[base + 2];
        v = sqrtf(m0 * m0 + m1 * m1 + m2 * m2 + 1e-12f);
      }
      invt[cd][r] = v;
    }
    __syncthreads();

    float acc[4][8];
#pragma unroll
    for (int i = 0; i < 4; ++i)
#pragma unroll
      for (int j = 0; j < 8; ++j) acc[i][j] = 0.f;

    for (int k = 0; k < 48; ++k) {
      float4 av  = *(const float4*)&invt[k][n0];
      float4 w0  = *(const float4*)&w_s[k * 128 + tx * 4];
      float4 w1v = *(const float4*)&w_s[k * 128 + 64 + tx * 4];
#pragma unroll
      for (int i = 0; i < 4; ++i) {
        float a = (i == 0) ? av.x : (i == 1) ? av.y : (i == 2) ? av.z : av.w;
        acc[i][0] = fmaf(a, w0.x,  acc[i][0]);
        acc[i][1] = fmaf(a, w0.y,  acc[i][1]);
        acc[i][2] = fmaf(a, w0.z,  acc[i][2]);
        acc[i][3] = fmaf(a, w0.w,  acc[i][3]);
        acc[i][4] = fmaf(a, w1v.x, acc[i][4]);
        acc[i][5] = fmaf(a, w1v.y, acc[i][5]);
        acc[i][6] = fmaf(a, w1v.z, acc[i][6]);
        acc[i][7] = fmaf(a, w1v.w, acc[i][7]);
      }
    }
    __syncthreads();   // all reads of w_s/invt done before xs overwrites them

    float4 bq0 = *(const float4*)(bo1 + tx * 4);
    float4 bq1 = *(const float4*)(bo1 + 64 + tx * 4);
#pragma unroll
    for (int i = 0; i < 4; ++i) {
      int row = n0 + i;
      int sw = (row & 7) << 4;
      float q0[4] = {silu_f(acc[i][0] + bq0.x), silu_f(acc[i][1] + bq0.y),
                     silu_f(acc[i][2] + bq0.z), silu_f(acc[i][3] + bq0.w)};
      float q1[4] = {silu_f(acc[i][4] + bq1.x), silu_f(acc[i][5] + bq1.y),
                     silu_f(acc[i][6] + bq1.z), silu_f(acc[i][7] + bq1.w)};
      union { __bf16 bb[4]; uint2 u; } H, L;
#pragma unroll
      for (int e = 0; e < 4; ++e) {
        __bf16 hv = (__bf16)q0[e];
        H.bb[e] = hv;
        L.bb[e] = (__bf16)(q0[e] - (float)hv);
      }
      *(uint2*)(xsh + ((row * 256 + tx * 8) ^ sw)) = H.u;
      *(uint2*)(xsl + ((row * 256 + tx * 8) ^ sw)) = L.u;
#pragma unroll
      for (int e = 0; e < 4; ++e) {
        __bf16 hv = (__bf16)q1[e];
        H.bb[e] = hv;
        L.bb[e] = (__bf16)(q1[e] - (float)hv);
      }
      *(uint2*)(xsh + ((row * 256 + 128 + tx * 8) ^ sw)) = H.u;
      *(uint2*)(xsl + ((row * 256 + 128 + tx * 8) ^ sw)) = L.u;
    }
  }
  __syncthreads();

  // ---------------- phase B: layer 2 MFMA ----------------
  int w = t >> 6, l = t & 63;
  int kg = l >> 4, ln = l & 15;
  {
    // A fragments from xs
    int arw = w * 16 + ln;
    int sw = (arw & 7) << 4;
    v8bf axh[4], axl[4];
#pragma unroll
    for (int kb = 0; kb < 4; ++kb) {
      int byt = arw * 256 + kb * 64 + kg * 16;
      axh[kb] = *(v8bf*)(xsh + (byt ^ sw));
      axl[kb] = *(v8bf*)(xsl + (byt ^ sw));
    }
    // stage kb0 of w2t
    {
      size_t p0 = (size_t)(w * 16 + ln) * 128 + kg * 8;
      size_t p1 = (size_t)((w + 4) * 16 + ln) * 128 + kg * 8;
      BsB[0][0][w][l]     = *(const v8bf*)(W2h + p0);
      BsB[0][0][w + 4][l] = *(const v8bf*)(W2h + p1);
      BsB[0][1][w][l]     = *(const v8bf*)(W2l + p0);
      BsB[0][1][w + 4][l] = *(const v8bf*)(W2l + p1);
    }
    __syncthreads();

    v4f acc[8];
    v4f z4 = {0.f, 0.f, 0.f, 0.f};
#pragma unroll
    for (int i = 0; i < 8; ++i) acc[i] = z4;

    for (int kb = 0; kb < 4; ++kb) {
      int cur = kb & 1;
      v8bf r0, r1, r2, r3;
      if (kb < 3) {
        size_t p0 = (size_t)(w * 16 + ln) * 128 + (kb + 1) * 32 + kg * 8;
        size_t p1 = (size_t)((w + 4) * 16 + ln) * 128 + (kb + 1) * 32 + kg * 8;
        r0 = *(const v8bf*)(W2h + p0);
        r1 = *(const v8bf*)(W2h + p1);
        r2 = *(const v8bf*)(W2l + p0);
        r3 = *(const v8bf*)(W2l + p1);
      }
#pragma unroll
      for (int nt = 0; nt < 8; ++nt) {
        v8bf bh = BsB[cur][0][nt][l];
        v8bf bl = BsB[cur][1][nt][l];
        acc[nt] = __builtin_amdgcn_mfma_f32_16x16x32_bf16(axh[kb], bh, acc[nt], 0, 0, 0);
        acc[nt] = __builtin_amdgcn_mfma_f32_16x16x32_bf16(axl[kb], bh, acc[nt], 0, 0, 0);
        acc[nt] = __builtin_amdgcn_mfma_f32_16x16x32_bf16(axh[kb], bl, acc[nt], 0, 0, 0);
      }
      if (kb < 3) {
        int nxt = cur ^ 1;
        BsB[nxt][0][w][l]     = r0;
        BsB[nxt][0][w + 4][l] = r1;
        BsB[nxt][1][w][l]     = r2;
        BsB[nxt][1][w + 4][l] = r3;
      }
      __syncthreads();
    }

    // epilogue: silu -> ys (overwrites BsB; all MFMA reads done past last barrier)
    int r0l = w * 16 + kg * 4;
#pragma unroll
    for (int nt = 0; nt < 8; ++nt) {
      float bv = bo2[nt * 16 + ln];
#pragma unroll
      for (int j = 0; j < 4; ++j) {
        float x = silu_f(acc[nt][j] + bv);
        int row = r0l + j;
        int byt = (row * 256 + (nt * 16 + ln) * 2) ^ ((row & 7) << 4);
        __bf16 hv = (__bf16)x;
        *(__bf16*)(ysh + byt) = hv;
        *(__bf16*)(ysl + byt) = (__bf16)(x - (float)hv);
      }
    }
  }
  __syncthreads();

  // ---------------- phase C: layer 3 MFMA (2 col chunks) ----------------
  {
    int arw = w * 16 + ln;
    int sw = (arw & 7) << 4;
    v8bf ayh[4], ayl[4];
#pragma unroll
    for (int kb = 0; kb < 4; ++kb) {
      int byt = arw * 256 + kb * 64 + kg * 16;
      ayh[kb] = *(v8bf*)(ysh + (byt ^ sw));
      ayl[kb] = *(v8bf*)(ysl + (byt ^ sw));
    }
    __syncthreads();  // ensure all frag reads done before BsC staging pattern races? (BsC in region1, ys in region2 — kept for ordering safety)

    for (int ch = 0; ch < 2; ++ch) {
      int cbase = ch * 128;
      {
        size_t p0 = (size_t)(cbase + w * 16 + ln) * 128 + kg * 8;
        size_t p1 = (size_t)(cbase + (w + 4) * 16 + ln) * 128 + kg * 8;
        BsC[0][0][w][l]     = *(const v8bf*)(W3h + p0);
        BsC[0][0][w + 4][l] = *(const v8bf*)(W3h + p1);
        BsC[0][1][w][l]     = *(const v8bf*)(W3l + p0);
        BsC[0][1][w + 4][l] = *(const v8bf*)(W3l + p1);
      }
      __syncthreads();

      v4f acc[8];
      v4f z4 = {0.f, 0.f, 0.f, 0.f};
#pragma unroll
      for (int i = 0; i < 8; ++i) acc[i] = z4;

      for (int kb = 0; kb < 4; ++kb) {
        int cur = kb & 1;
        v8bf r0, r1, r2, r3;
        if (kb < 3) {
          size_t p0 = (size_t)(cbase + w * 16 + ln) * 128 + (kb + 1) * 32 + kg * 8;
          size_t p1 = (size_t)(cbase + (w + 4) * 16 + ln) * 128 + (kb + 1) * 32 + kg * 8;
          r0 = *(const v8bf*)(W3h + p0);
          r1 = *(const v8bf*)(W3h + p1);
          r2 = *(const v8bf*)(W3l + p0);
          r3 = *(const v8bf*)(W3l + p1);
        }
#pragma unroll
        for (int nt = 0; nt < 8; ++nt) {
          v8bf bh = BsC[cur][0][nt][l];
          v8bf bl = BsC[cur][1][nt][l];
          acc[nt] = __builtin_amdgcn_mfma_f32_16x16x32_bf16(ayh[kb], bh, acc[nt], 0, 0, 0);
          acc[nt] = __builtin_amdgcn_mfma_f32_16x16x32_bf16(ayl[kb], bh, acc[nt], 0, 0, 0);
          acc[nt] = __builtin_amdgcn_mfma_f32_16x16x32_bf16(ayh[kb], bl, acc[nt], 0, 0, 0);
        }
        if (kb < 3) {
          int nxt = cur ^ 1;
          BsC[nxt][0][w][l]     = r0;
          BsC[nxt][0][w + 4][l] = r1;
          BsC[nxt][1][w][l]     = r2;
          BsC[nxt][1][w + 4][l] = r3;
        }
        __syncthreads();
      }

      int r0g = rbase + w * 16 + kg * 4;
#pragma unroll
      for (int nt = 0; nt < 8; ++nt) {
        float bv = bo3[cbase + nt * 16 + ln];
#pragma unroll
        for (int j = 0; j < 4; ++j) {
          out[(size_t)(r0g + j) * 256 + cbase + nt * 16 + ln] = acc[nt][j] + bv;
        }
      }
    }
  }
}

extern "C" void kernel_launch(void* const* d_in, const int* in_sizes, int n_in,
                              void* d_out, int out_size, void* d_ws, size_t ws_size,
                              hipStream_t stream) {
  const float* h        = (const float*)d_in[0];
  const float* h_full   = (const float*)d_in[1];
  const int*   z        = (const int*)d_in[2];
  const float* e_feat   = (const float*)d_in[4];
  const int*   abs_idx  = (const int*)d_in[5];
  const int*   att_dst  = (const int*)d_in[6];
  const float* att_dist = (const float*)d_in[7];
  const float* att_vec  = (const float*)d_in[8];
  const float* w_zemb   = (const float*)d_in[9];
  const float* w1_rad   = (const float*)d_in[10];
  const float* b1_rad   = (const float*)d_in[11];
  const float* w2_rad   = (const float*)d_in[12];
  const float* b2_rad   = (const float*)d_in[13];
  const float* wg1      = (const float*)d_in[14];
  const float* bg1      = (const float*)d_in[15];
  const float* wg2      = (const float*)d_in[16];
  const float* bg2      = (const float*)d_in[17];
  const float* we1      = (const float*)d_in[18];
  const float* be1      = (const float*)d_in[19];
  const float* we2      = (const float*)d_in[20];
  const float* be2      = (const float*)d_in[21];
  const float* wo1      = (const float*)d_in[22];
  const float* bo1      = (const float*)d_in[23];
  const float* wo2      = (const float*)d_in[24];
  const float* bo2      = (const float*)d_in[25];
  const float* wo3      = (const float*)d_in[26];
  const float* bo3      = (const float*)d_in[27];
  float* out = (float*)d_out;

  float* meta_f  = (float*)d_ws;                 // MAXACT*4
  float* vabs    = meta_f + MAXACT * 4;          // 64*80
  float* sfull   = vabs + NB * OD_;              // 512*80
  float* habs_g  = sfull + NE_ * OD_;            // 64*128
  __bf16* w2t_h  = (__bf16*)(habs_g + NB * 128); // 128*128 bf16
  __bf16* w2t_l  = w2t_h + 128 * 128;
  __bf16* w3t_h  = w2t_l + 128 * 128;            // 256*128 bf16
  __bf16* w3t_l  = w3t_h + 256 * 128;
  int* widx   = (int*)(w3t_l + 256 * 128);       // 8192
  int* active = widx + FLAT;                     // 4096
  int* meta_b = active + MAXACT;                 // 4096
  int* count  = meta_b + MAXACT;                 // 1 (+pad)
  float* big  = (float*)(count + 15);
  __bf16* ah_glob  = (__bf16*)big;               // MAXACT*128
  __bf16* al_glob  = ah_glob + MAXACT * 128;     // MAXACT*128
  float* coef_glob = (float*)(al_glob + MAXACT * 128);    // MAXACT*192
  __bf16* w2rt_h   = (__bf16*)(coef_glob + MAXACT * 192); // 4608*128
  __bf16* w2rt_l   = w2rt_h + 4608 * 128;
  float* part2     = (float*)(w2rt_l + 4608 * 128);       // MAXACT*400 (6.6 MB)

  k_prep<<<359, 256, 0, stream>>>(w2_rad, wo2, wo3, abs_idx, h, wg1,
                                  e_feat, we1, be1, we2, be2,
                                  w2rt_h, w2rt_l, w2t_h, w2t_l, w3t_h, w3t_l,
                                  habs_g, vabs, widx, count, sfull);
  k_scatter<<<16, 256, 0, stream>>>(att_dst, widx);
  k_build<<<32, 256, 0, stream>>>(widx, active, count);
  k_node4<<<1024, 128, 0, stream>>>(count, active, widx, att_dist, att_vec, z, w_zemb,
                                    abs_idx, w1_rad, b1_rad, h, habs_g, wg1, bg1, wg2, bg2,
                                    h_full, ah_glob, al_glob, coef_glob, meta_f, meta_b);
  k_mrgemm2<<<dim3(12, 32), 256, 0, stream>>>(count, ah_glob, al_glob, w2rt_h, w2rt_l,
                                              b2_rad, coef_glob, part2);
  k_combine<<<2048, 256, 0, stream>>>(count, part2, meta_f, meta_b, vabs);
  k_head<<<512, 256, 0, stream>>>(vabs, sfull, wo1, bo1, w2t_h, w2t_l, bo2,
                                  w3t_h, w3t_l, bo3, out);
}

// Round 6
// 215.967 us; speedup vs baseline: 2.1051x; 2.1051x over previous
//
#include <hip/hip_runtime.h>
#include <math.h>

#define FLAT   8192
#define NB     64
#define OD_    80
#define NE_    512
#define EATT_  4096
#define MAXACT 4096
// part: 1088 floats/node of contraction partials, written by k_mrgemm with
// plain stores (no atomics), reduced by k_combine:
//   [0..767]   24 cc-slices x 32 out_s slots
//   [768..895]  8 cc-slices x 16 q slots
//   [896..1087] 4 cc-slices x 48 D-term slots (comp*16+o)
#define PARTW 1088

typedef __bf16 v8bf __attribute__((ext_vector_type(8)));
typedef float  v4f  __attribute__((ext_vector_type(4)));

__device__ __forceinline__ float silu_f(float x) { return x / (1.f + __expf(-x)); }
__device__ __forceinline__ float sigm_f(float x) { return 1.f / (1.f + __expf(-x)); }

// ================= k_prep: init + gabs + scales + coalesced weight transposes =================
// blocks 0..35  : w2_rad -> w2rt hi/lo [n][k]
// block  36     : wo2 -> w2t hi/lo
// blocks 37..38 : wo3 -> w3t hi/lo
// blocks 39..70 : gabs (2 batches per block)
// blocks 71..102: init (widx=-1, vabs=0, count=0)
// blocks 103..358: scales (2 rows per block)
__device__ __forceinline__ void transpose_split(const float* __restrict__ src, int ld,
                                                int nbase, __bf16* wh, __bf16* wl,
                                                float (*lds)[129]) {
  int t = threadIdx.x;  // 256
#pragma unroll
  for (int it = 0; it < 16; ++it) {
    int idx = it * 256 + t;
    int r = idx >> 5, c4 = idx & 31;
    float4 v = *(const float4*)(src + (size_t)r * ld + nbase + c4 * 4);
    lds[r][c4 * 4 + 0] = v.x;
    lds[r][c4 * 4 + 1] = v.y;
    lds[r][c4 * 4 + 2] = v.z;
    lds[r][c4 * 4 + 3] = v.w;
  }
  __syncthreads();
  int n = t >> 1, kh = (t & 1) * 64;
  union { __bf16 b[64]; uint4 u[8]; } H, L;
#pragma unroll
  for (int k = 0; k < 64; ++k) {
    float v = lds[kh + k][n];
    __bf16 hv = (__bf16)v;
    H.b[k] = hv;
    L.b[k] = (__bf16)(v - (float)hv);
  }
  uint4* ph = (uint4*)(wh + (size_t)(nbase + n) * 128 + kh);
  uint4* pl = (uint4*)(wl + (size_t)(nbase + n) * 128 + kh);
#pragma unroll
  for (int i = 0; i < 8; ++i) { ph[i] = H.u[i]; pl[i] = L.u[i]; }
}

__global__ __launch_bounds__(256) void k_prep(
    const float* __restrict__ w2_rad, const float* __restrict__ wo2,
    const float* __restrict__ wo3,
    const int* __restrict__ abs_idx, const float* __restrict__ h,
    const float* __restrict__ wg1,
    const float* __restrict__ e_feat,
    const float* __restrict__ we1, const float* __restrict__ be1,
    const float* __restrict__ we2, const float* __restrict__ be2,
    __bf16* w2rt_h, __bf16* w2rt_l, __bf16* w2t_h, __bf16* w2t_l,
    __bf16* w3t_h, __bf16* w3t_l,
    float* habs_g, float* vabs, int* widx, int* count, float* sfull) {
  __shared__ float lds[128][129];
  int bid = blockIdx.x;
  int t = threadIdx.x;
  if (bid < 36) {
    transpose_split(w2_rad, 4608, bid * 128, w2rt_h, w2rt_l, lds);
  } else if (bid < 37) {
    transpose_split(wo2, 128, 0, w2t_h, w2t_l, lds);
  } else if (bid < 39) {
    transpose_split(wo3, 256, (bid - 37) * 128, w3t_h, w3t_l, lds);
  } else if (bid < 71) {
    float* hs = &lds[0][0];  // [2][128]
    int half = t >> 7, tt = t & 127;
    int b = (bid - 39) * 2 + half;
    int nabs = abs_idx[b];
    hs[half * 128 + tt] = h[(size_t)(b * 128 + nabs) * 128 + tt];
    __syncthreads();
    float g = 0.f;
    for (int c = 0; c < 128; ++c) g = fmaf(hs[half * 128 + c], wg1[c * 128 + tt], g);
    habs_g[b * 128 + tt] = g;
  } else if (bid < 103) {
    int g = (bid - 71) * 256 + t;
    if (g < FLAT) widx[g] = -1;
    if (g < NB * OD_) vabs[g] = 0.f;
    if (g == 0) *count = 0;
  } else {
    // scales: 2 rows per block
    float* hid = &lds[0][0];  // [2][128]
    int half = t >> 7, tt = t & 127;
    int row = (bid - 103) * 2 + half;
    const float* ef = e_feat + row * 16;
    float s = be1[tt];
    for (int k = 0; k < 16; ++k) s = fmaf(ef[k], we1[k * 128 + tt], s);
    hid[half * 128 + tt] = silu_f(s);
    __syncthreads();
    if (tt < 48) {
      float o = be2[tt];
      for (int k = 0; k < 128; ++k) o = fmaf(hid[half * 128 + k], we2[k * 48 + tt], o);
      if (tt < 32) sfull[row * 80 + tt] = o;
      else {
        int oo = tt - 32;
        sfull[row * 80 + 32 + oo * 3 + 0] = o;
        sfull[row * 80 + 32 + oo * 3 + 1] = o;
        sfull[row * 80 + 32 + oo * 3 + 2] = o;
      }
    }
  }
}

// ---------------- scatter: last-write-wins == max edge index ----------------
__global__ void k_scatter(const int* __restrict__ att_dst, int* widx) {
  int i = blockIdx.x * 256 + threadIdx.x;
  if (i < EATT_) atomicMax(&widx[att_dst[i]], i);
}

// ---------------- compact active-node list ----------------
__global__ void k_build(const int* __restrict__ widx, int* active, int* count) {
  int j = blockIdx.x * 256 + threadIdx.x;
  if (j < FLAT && widx[j] >= 0) {
    int p = atomicAdd(count, 1);
    active[p] = j;
  }
}

// ======== k_node4: 4 nodes per block; shared wg1/w1_rad column loads ========
__global__ __launch_bounds__(128) void k_node4(
    const int* __restrict__ count, const int* __restrict__ active,
    const int* __restrict__ widx,
    const float* __restrict__ att_dist, const float* __restrict__ att_vec,
    const int* __restrict__ z, const float* __restrict__ w_zemb,
    const int* __restrict__ abs_idx,
    const float* __restrict__ w1_rad, const float* __restrict__ b1_rad,
    const float* __restrict__ h, const float* __restrict__ habs_g,
    const float* __restrict__ wg1, const float* __restrict__ bg1,
    const float* __restrict__ wg2, const float* __restrict__ bg2,
    const float* __restrict__ h_full,
    __bf16* ah_glob, __bf16* al_glob,
    float* coef_glob, float* meta_f, int* meta_b) {
  int cnt = *count;
  int pbase = blockIdx.x * 4;
  if (pbase >= cnt) return;
  int t = threadIdx.x;  // 128

  __shared__ float win[4][49];
  __shared__ float yv_s[4][3];
  __shared__ float sh_d[4];
  __shared__ float red[4][128];
  __shared__ float hsh[4][128];

  bool ok[4];
  int jj[4], ee[4], bb[4];
  float isab[4];
#pragma unroll
  for (int q = 0; q < 4; ++q) {
    int pos = pbase + q;
    ok[q] = pos < cnt;
    jj[q] = ok[q] ? active[pos] : 0;
    ee[q] = ok[q] ? widx[jj[q]] : 0;
    if (ee[q] < 0) ee[q] = 0;
    bb[q] = jj[q] >> 7;
    isab[q] = ((jj[q] & 127) == abs_idx[bb[q]]) ? 1.f : 0.f;
  }

  if (t < 4) {
    int q = t;
    float d = att_dist[ee[q]];
    sh_d[q] = d;
    float eps = fmaxf(d, 1e-8f);
    const float s3 = 1.7320508075688772f;
    yv_s[q][0] = s3 * att_vec[ee[q] * 3 + 0] / eps;
    yv_s[q][1] = s3 * att_vec[ee[q] * 3 + 1] / eps;
    yv_s[q][2] = s3 * att_vec[ee[q] * 3 + 2] / eps;
  }
#pragma unroll
  for (int q = 0; q < 4; ++q) {
    if (t < 32) win[q][t] = w_zemb[z[jj[q]] * 32 + t];
    if (t == 32) win[q][32] = isab[q];
    if (t >= 33 && t < 49) {
      int k = t - 33;
      float d = att_dist[ee[q]];
      float x = (d - (float)k * (1.f / 3.f)) * 3.f;  // width = 1/3
      win[q][t] = __expf(-0.5f * x * x);
    }
    hsh[q][t] = h[(size_t)jj[q] * 128 + t];
  }
  __syncthreads();

  // hidden a = silu(win @ w1_rad + b1) per node, w1_rad column loaded once
  {
    float s[4];
    float bv = b1_rad[t];
#pragma unroll
    for (int q = 0; q < 4; ++q) s[q] = bv;
    for (int k = 0; k < 49; ++k) {
      float wv = w1_rad[k * 128 + t];
#pragma unroll
      for (int q = 0; q < 4; ++q) s[q] = fmaf(win[q][k], wv, s[q]);
    }
#pragma unroll
    for (int q = 0; q < 4; ++q) {
      if (ok[q]) {
        float av = silu_f(s[q]);
        __bf16 hv = (__bf16)av;
        ah_glob[(size_t)(pbase + q) * 128 + t] = hv;
        al_glob[(size_t)(pbase + q) * 128 + t] = (__bf16)(av - (float)hv);
      }
    }
  }

  // gate MLP hidden (273 -> 128), wg1 column loaded once per c
  {
    float g[4];
#pragma unroll
    for (int q = 0; q < 4; ++q) g[q] = bg1[t] + habs_g[bb[q] * 128 + t];
    for (int c = 0; c < 128; ++c) {
      float wv = wg1[(128 + c) * 128 + t];
#pragma unroll
      for (int q = 0; q < 4; ++q) g[q] = fmaf(hsh[q][c], wv, g[q]);
    }
    for (int k = 0; k < 16; ++k) {
      float wv = wg1[(256 + k) * 128 + t];
#pragma unroll
      for (int q = 0; q < 4; ++q) g[q] = fmaf(win[q][33 + k], wv, g[q]);
    }
    {
      float wv = wg1[272 * 128 + t];
#pragma unroll
      for (int q = 0; q < 4; ++q) g[q] = fmaf(isab[q], wv, g[q]);
    }
    float w2v = wg2[t];
#pragma unroll
    for (int q = 0; q < 4; ++q) red[q][t] = silu_f(g[q]) * w2v;
  }
  __syncthreads();

  // per-node contraction coefficients: [s1(64), p*inv_s3(32), v1(96)]
#pragma unroll
  for (int q = 0; q < 4; ++q) {
    if (!ok[q]) continue;
    int pos = pbase + q;
    const float* hf = h_full + (size_t)jj[q] * 160;
    if (t < 64) coef_glob[pos * 192 + t] = hf[t];
    if (t >= 64 && t < 96) {
      int i = t - 64;
      float pv = hf[64 + i * 3 + 0] * yv_s[q][0] + hf[64 + i * 3 + 1] * yv_s[q][1] +
                 hf[64 + i * 3 + 2] * yv_s[q][2];
      coef_glob[pos * 192 + t] = pv * 0.5773502691896258f;
    }
    if (t < 96) coef_glob[pos * 192 + 96 + t] = hf[64 + t];
  }

  if (t < 4) {
    int q = t;
    if (ok[q]) {
      int pos = pbase + q;
      float tot = 0.f;
      for (int k = 0; k < 128; ++k) tot += red[q][k];
      tot += bg2[0];
      float gate = sigm_f(tot);
      float d = sh_d[q];
      float env = (d < 5.f) ? 0.5f * (__cosf(3.14159265358979323846f * d * 0.2f) + 1.f) : 0.f;
      meta_f[pos * 4 + 0] = yv_s[q][0];
      meta_f[pos * 4 + 1] = yv_s[q][1];
      meta_f[pos * 4 + 2] = yv_s[q][2];
      meta_f[pos * 4 + 3] = gate * env;
      meta_b[pos] = bb[q];
    }
  }
}

// ---------------- split-bf16 MFMA radial GEMM + fused contraction (R4-proven) ----------------
// tpw = a[node][128k] @ w2rt[4608n][128k]^T + b2, contracted on the fly.
// Partials go to part[node][1088] via plain coalesced stores; k_combine reduces.
// NOTE (R5 lesson, rule #20): A-fragment arrays must be indexed with
// compile-time kb only — explicit register rotation, no Af[kb] with runtime kb.
__global__ __launch_bounds__(256) void k_mrgemm(
    const int* __restrict__ count,
    const __bf16* Ah, const __bf16* Al,
    const __bf16* __restrict__ Bh, const __bf16* __restrict__ Bl,
    const float* __restrict__ b2, const float* __restrict__ coef_glob,
    float* __restrict__ part) {
  int cc = blockIdx.x;            // 0..35
  int nbase = blockIdx.y * 128;   // 32 y-blocks
  int cnt = *count;
  if (nbase >= cnt) return;
  int t = threadIdx.x;
  int w = t >> 6, l = t & 63;
  int kg = l >> 4, ln = l & 15;
  int cbase = cc * 128;

  __shared__ v8bf Bs[2][2][8][64];   // [buf][plane][nt][lane] 32 KB

  size_t brow0 = (size_t)(cbase + w * 16 + ln) * 128 + kg * 8;
  size_t brow1 = (size_t)(cbase + (w + 4) * 16 + ln) * 128 + kg * 8;
  size_t arow0 = (size_t)(nbase + (2 * w) * 16 + ln) * 128 + kg * 8;
  size_t arow1 = (size_t)(nbase + (2 * w + 1) * 16 + ln) * 128 + kg * 8;

  v8bf rb0 = *(const v8bf*)(Bh + brow0);
  v8bf rb1 = *(const v8bf*)(Bh + brow1);
  v8bf rb2 = *(const v8bf*)(Bl + brow0);
  v8bf rb3 = *(const v8bf*)(Bl + brow1);
  v8bf ah0 = *(const v8bf*)(Ah + arow0);
  v8bf al0 = *(const v8bf*)(Al + arow0);
  v8bf ah1 = *(const v8bf*)(Ah + arow1);
  v8bf al1 = *(const v8bf*)(Al + arow1);
  Bs[0][0][w][l]     = rb0;
  Bs[0][0][w + 4][l] = rb1;
  Bs[0][1][w][l]     = rb2;
  Bs[0][1][w + 4][l] = rb3;
  __syncthreads();

  v4f acc[2][8];
  v4f z4 = {0.f, 0.f, 0.f, 0.f};
#pragma unroll
  for (int i = 0; i < 2; ++i)
#pragma unroll
    for (int j = 0; j < 8; ++j) acc[i][j] = z4;

  for (int kb = 0; kb < 4; ++kb) {
    int cur = kb & 1;
    v8bf nb0, nb1, nb2, nb3, nh0, nl0, nh1, nl1;
    if (kb < 3) {
      int off = (kb + 1) * 32;
      nb0 = *(const v8bf*)(Bh + brow0 + off);
      nb1 = *(const v8bf*)(Bh + brow1 + off);
      nb2 = *(const v8bf*)(Bl + brow0 + off);
      nb3 = *(const v8bf*)(Bl + brow1 + off);
      nh0 = *(const v8bf*)(Ah + arow0 + off);
      nl0 = *(const v8bf*)(Al + arow0 + off);
      nh1 = *(const v8bf*)(Ah + arow1 + off);
      nl1 = *(const v8bf*)(Al + arow1 + off);
    }
#pragma unroll
    for (int nt = 0; nt < 8; ++nt) {
      v8bf bh = Bs[cur][0][nt][l];
      v8bf bl = Bs[cur][1][nt][l];
      acc[0][nt] = __builtin_amdgcn_mfma_f32_16x16x32_bf16(ah0, bh, acc[0][nt], 0, 0, 0);
      acc[0][nt] = __builtin_amdgcn_mfma_f32_16x16x32_bf16(al0, bh, acc[0][nt], 0, 0, 0);
      acc[0][nt] = __builtin_amdgcn_mfma_f32_16x16x32_bf16(ah0, bl, acc[0][nt], 0, 0, 0);
      acc[1][nt] = __builtin_amdgcn_mfma_f32_16x16x32_bf16(ah1, bh, acc[1][nt], 0, 0, 0);
      acc[1][nt] = __builtin_amdgcn_mfma_f32_16x16x32_bf16(al1, bh, acc[1][nt], 0, 0, 0);
      acc[1][nt] = __builtin_amdgcn_mfma_f32_16x16x32_bf16(ah1, bl, acc[1][nt], 0, 0, 0);
    }
    if (kb < 3) {
      int nxt = cur ^ 1;
      Bs[nxt][0][w][l]     = nb0;
      Bs[nxt][0][w + 4][l] = nb1;
      Bs[nxt][1][w][l]     = nb2;
      Bs[nxt][1][w + 4][l] = nb3;
      ah0 = nh0; al0 = nl0; ah1 = nh1; al1 = nl1;
    }
    __syncthreads();
  }

  float b2v[8];
#pragma unroll
  for (int nt = 0; nt < 8; ++nt) b2v[nt] = b2[cbase + nt * 16 + ln];

#pragma unroll
  for (int mi = 0; mi < 2; ++mi) {
    int nodeb = nbase + (2 * w + mi) * 16 + kg * 4;
#pragma unroll
    for (int j = 0; j < 4; ++j) {
      int nd = nodeb + j;
      if (nd >= cnt) continue;
      const float* cf = coef_glob + (size_t)nd * 192;
      if (cc < 24) {
        float s0 = 0.f, s1 = 0.f;
#pragma unroll
        for (int m = 0; m < 4; ++m) {
          float c = cf[cc * 4 + m];
          s0 = fmaf(acc[mi][2 * m][j] + b2v[2 * m], c, s0);
          s1 = fmaf(acc[mi][2 * m + 1][j] + b2v[2 * m + 1], c, s1);
        }
        float* pp = part + (size_t)nd * PARTW + cc * 32 + ln;
        pp[0]  = s0;
        pp[16] = s1;
      } else if (cc < 32) {
        float s = 0.f;
#pragma unroll
        for (int nt = 0; nt < 8; ++nt)
          s = fmaf(acc[mi][nt][j] + b2v[nt], cf[(cc - 24) * 8 + nt], s);
        part[(size_t)nd * PARTW + 768 + (cc - 24) * 16 + ln] = s;
      } else {
        float s0 = 0.f, s1 = 0.f, s2 = 0.f;
#pragma unroll
        for (int nt = 0; nt < 8; ++nt) {
          float x = acc[mi][nt][j] + b2v[nt];
          const float* c3 = cf + 96 + ((cc - 32) * 8 + nt) * 3;
          s0 = fmaf(x, c3[0], s0);
          s1 = fmaf(x, c3[1], s1);
          s2 = fmaf(x, c3[2], s2);
        }
        float* pp = part + (size_t)nd * PARTW + 896 + (cc - 32) * 48 + ln;
        pp[0]  = s0;
        pp[16] = s1;
        pp[32] = s2;
      }
    }
  }
}

// ---------------- combine part slices -> v_abs[b][80] ----------------
__global__ void k_combine(const int* __restrict__ count, const float* __restrict__ part,
                          const float* __restrict__ meta_f, const int* __restrict__ meta_b,
                          float* vabs) {
  int t = threadIdx.x;
  int pos = blockIdx.x * 2 + (t >> 7);
  int slot = t & 127;
  if (pos >= *count || slot >= 96) return;
  const float* pp = part + (size_t)pos * PARTW;
  float s = 0.f;
  if (slot < 32) {
#pragma unroll
    for (int c = 0; c < 24; ++c) s += pp[c * 32 + slot];
  } else if (slot < 48) {
#pragma unroll
    for (int c = 0; c < 8; ++c) s += pp[768 + c * 16 + (slot - 32)];
  } else {
#pragma unroll
    for (int c = 0; c < 4; ++c) s += pp[896 + c * 48 + (slot - 48)];
  }
  float sc = meta_f[pos * 4 + 3] * 0.10206207261596577f;  // gate*env / sqrt(96)
  float* vb = vabs + meta_b[pos] * 80;
  if (slot < 32) {
    unsafeAtomicAdd(&vb[slot], s * sc);
  } else if (slot < 48) {
    int o = slot - 32;
    float q = s * sc;
    unsafeAtomicAdd(&vb[32 + o * 3 + 0], q * meta_f[pos * 4 + 0]);
    unsafeAtomicAdd(&vb[32 + o * 3 + 1], q * meta_f[pos * 4 + 1]);
    unsafeAtomicAdd(&vb[32 + o * 3 + 2], q * meta_f[pos * 4 + 2]);
  } else {
    int s2 = slot - 48;          // comp*16 + o
    int comp = s2 >> 4, o = s2 & 15;
    unsafeAtomicAdd(&vb[32 + o * 3 + comp], s * sc);
  }
}

// ================= k_head: hg1 + head layer2 + head layer3, fused per 64 rows =================
// Phase A: inv build + (64x48)@wo1 fp32 GEMM + silu -> xs (LDS bf16 hi/lo, swizzled)
// Phase B: xs @ w2t^T (split-bf16 MFMA, K=128) + silu -> ys (LDS)
// Phase C: ys @ w3t^T (2 col-chunks of 128) + bo3 -> out
// LDS arena 68 KB, phase-aliased. Swizzle: byte ^= (row&7)<<4 (rows are 256 B).
__global__ __launch_bounds__(256) void k_head(
    const float* __restrict__ vabs, const float* __restrict__ sfull,
    const float* __restrict__ wo1, const float* __restrict__ bo1,
    const __bf16* __restrict__ W2h, const __bf16* __restrict__ W2l,
    const float* __restrict__ bo2,
    const __bf16* __restrict__ W3h, const __bf16* __restrict__ W3l,
    const float* __restrict__ bo3,
    float* __restrict__ out) {
  __shared__ __align__(16) char arena[69632];
  float* w_s = (float*)arena;
  float (*invt)[64] = (float(*)[64])(arena + 24576);
  float* va = (float*)(arena + 36864);
  char* xsh = arena;
  char* xsl = arena + 16384;
  v8bf (*BsB)[2][8][64] = (v8bf(*)[2][8][64])(arena + 36864);
  char* ysh = arena + 36864;
  char* ysl = arena + 53248;
  v8bf (*BsC)[2][8][64] = (v8bf(*)[2][8][64])arena;

  int rbase = blockIdx.x * 64;   // 512 blocks
  int b = rbase >> 9;
  int e0 = rbase & 511;
  int t = threadIdx.x;

  // ---------------- phase A (verbatim hg1 math) ----------------
  {
    int tx = t & 15, ty = t >> 4;
    int n0 = ty * 4;
    if (t < 80) va[t] = vabs[b * 80 + t];
    {
      const float4* wg = (const float4*)wo1;
      float4* ws4 = (float4*)w_s;
#pragma unroll
      for (int it = 0; it < 6; ++it) ws4[t + it * 256] = wg[t + it * 256];
    }
    __syncthreads();

    for (int idx = t; idx < 48 * 64; idx += 256) {
      int cd = idx >> 6, r = idx & 63;
      const float* sf = sfull + (size_t)(e0 + r) * 80;
      float v;
      if (cd < 32) v = va[cd] * sf[cd];
      else {
        int base = 32 + (cd - 32) * 3;
        float m0 = va[base + 0] * sf[base + 0];
        float m1 = va[base + 1] * sf[base + 1];
        float m2 = va[base + 2] * sf[base + 2];
        v = sqrtf(m0 * m0 + m1 * m1 + m2 * m2 + 1e-12f);
      }
      invt[cd][r] = v;
    }
    __syncthreads();

    float acc[4][8];
#pragma unroll
    for (int i = 0; i < 4; ++i)
#pragma unroll
      for (int j = 0; j < 8; ++j) acc[i][j] = 0.f;

    for (int k = 0; k < 48; ++k) {
      float4 av  = *(const float4*)&invt[k][n0];
      float4 w0  = *(const float4*)&w_s[k * 128 + tx * 4];
      float4 w1v = *(const float4*)&w_s[k * 128 + 64 + tx * 4];
#pragma unroll
      for (int i = 0; i < 4; ++i) {
        float a = (i == 0) ? av.x : (i == 1) ? av.y : (i == 2) ? av.z : av.w;
        acc[i][0] = fmaf(a, w0.x,  acc[i][0]);
        acc[i][1] = fmaf(a, w0.y,  acc[i][1]);
        acc[i][2] = fmaf(a, w0.z,  acc[i][2]);
        acc[i][3] = fmaf(a, w0.w,  acc[i][3]);
        acc[i][4] = fmaf(a, w1v.x, acc[i][4]);
        acc[i][5] = fmaf(a, w1v.y, acc[i][5]);
        acc[i][6] = fmaf(a, w1v.z, acc[i][6]);
        acc[i][7] = fmaf(a, w1v.w, acc[i][7]);
      }
    }
    __syncthreads();   // all reads of w_s/invt done before xs overwrites them

    float4 bq0 = *(const float4*)(bo1 + tx * 4);
    float4 bq1 = *(const float4*)(bo1 + 64 + tx * 4);
#pragma unroll
    for (int i = 0; i < 4; ++i) {
      int row = n0 + i;
      int sw = (row & 7) << 4;
      float q0[4] = {silu_f(acc[i][0] + bq0.x), silu_f(acc[i][1] + bq0.y),
                     silu_f(acc[i][2] + bq0.z), silu_f(acc[i][3] + bq0.w)};
      float q1[4] = {silu_f(acc[i][4] + bq1.x), silu_f(acc[i][5] + bq1.y),
                     silu_f(acc[i][6] + bq1.z), silu_f(acc[i][7] + bq1.w)};
      union { __bf16 bb[4]; uint2 u; } H, L;
#pragma unroll
      for (int e = 0; e < 4; ++e) {
        __bf16 hv = (__bf16)q0[e];
        H.bb[e] = hv;
        L.bb[e] = (__bf16)(q0[e] - (float)hv);
      }
      *(uint2*)(xsh + ((row * 256 + tx * 8) ^ sw)) = H.u;
      *(uint2*)(xsl + ((row * 256 + tx * 8) ^ sw)) = L.u;
#pragma unroll
      for (int e = 0; e < 4; ++e) {
        __bf16 hv = (__bf16)q1[e];
        H.bb[e] = hv;
        L.bb[e] = (__bf16)(q1[e] - (float)hv);
      }
      *(uint2*)(xsh + ((row * 256 + 128 + tx * 8) ^ sw)) = H.u;
      *(uint2*)(xsl + ((row * 256 + 128 + tx * 8) ^ sw)) = L.u;
    }
  }
  __syncthreads();

  // ---------------- phase B: layer 2 MFMA ----------------
  int w = t >> 6, l = t & 63;
  int kg = l >> 4, ln = l & 15;
  {
    int arw = w * 16 + ln;
    int sw = (arw & 7) << 4;
    v8bf axh[4], axl[4];
#pragma unroll
    for (int kb = 0; kb < 4; ++kb) {
      int byt = arw * 256 + kb * 64 + kg * 16;
      axh[kb] = *(v8bf*)(xsh + (byt ^ sw));
      axl[kb] = *(v8bf*)(xsl + (byt ^ sw));
    }
    {
      size_t p0 = (size_t)(w * 16 + ln) * 128 + kg * 8;
      size_t p1 = (size_t)((w + 4) * 16 + ln) * 128 + kg * 8;
      BsB[0][0][w][l]     = *(const v8bf*)(W2h + p0);
      BsB[0][0][w + 4][l] = *(const v8bf*)(W2h + p1);
      BsB[0][1][w][l]     = *(const v8bf*)(W2l + p0);
      BsB[0][1][w + 4][l] = *(const v8bf*)(W2l + p1);
    }
    __syncthreads();

    v4f acc[8];
    v4f z4 = {0.f, 0.f, 0.f, 0.f};
#pragma unroll
    for (int i = 0; i < 8; ++i) acc[i] = z4;

#pragma unroll
    for (int kb = 0; kb < 4; ++kb) {
      int cur = kb & 1;
      v8bf r0, r1, r2, r3;
      if (kb < 3) {
        size_t p0 = (size_t)(w * 16 + ln) * 128 + (kb + 1) * 32 + kg * 8;
        size_t p1 = (size_t)((w + 4) * 16 + ln) * 128 + (kb + 1) * 32 + kg * 8;
        r0 = *(const v8bf*)(W2h + p0);
        r1 = *(const v8bf*)(W2h + p1);
        r2 = *(const v8bf*)(W2l + p0);
        r3 = *(const v8bf*)(W2l + p1);
      }
#pragma unroll
      for (int nt = 0; nt < 8; ++nt) {
        v8bf bh = BsB[cur][0][nt][l];
        v8bf bl = BsB[cur][1][nt][l];
        acc[nt] = __builtin_amdgcn_mfma_f32_16x16x32_bf16(axh[kb], bh, acc[nt], 0, 0, 0);
        acc[nt] = __builtin_amdgcn_mfma_f32_16x16x32_bf16(axl[kb], bh, acc[nt], 0, 0, 0);
        acc[nt] = __builtin_amdgcn_mfma_f32_16x16x32_bf16(axh[kb], bl, acc[nt], 0, 0, 0);
      }
      if (kb < 3) {
        int nxt = cur ^ 1;
        BsB[nxt][0][w][l]     = r0;
        BsB[nxt][0][w + 4][l] = r1;
        BsB[nxt][1][w][l]     = r2;
        BsB[nxt][1][w + 4][l] = r3;
      }
      __syncthreads();
    }

    int r0l = w * 16 + kg * 4;
#pragma unroll
    for (int nt = 0; nt < 8; ++nt) {
      float bv = bo2[nt * 16 + ln];
#pragma unroll
      for (int j = 0; j < 4; ++j) {
        float x = silu_f(acc[nt][j] + bv);
        int row = r0l + j;
        int byt = (row * 256 + (nt * 16 + ln) * 2) ^ ((row & 7) << 4);
        __bf16 hv = (__bf16)x;
        *(__bf16*)(ysh + byt) = hv;
        *(__bf16*)(ysl + byt) = (__bf16)(x - (float)hv);
      }
    }
  }
  __syncthreads();

  // ---------------- phase C: layer 3 MFMA (2 col chunks) ----------------
  {
    int arw = w * 16 + ln;
    int sw = (arw & 7) << 4;
    v8bf ayh[4], ayl[4];
#pragma unroll
    for (int kb = 0; kb < 4; ++kb) {
      int byt = arw * 256 + kb * 64 + kg * 16;
      ayh[kb] = *(v8bf*)(ysh + (byt ^ sw));
      ayl[kb] = *(v8bf*)(ysl + (byt ^ sw));
    }
    __syncthreads();

    for (int ch = 0; ch < 2; ++ch) {
      int cbase = ch * 128;
      {
        size_t p0 = (size_t)(cbase + w * 16 + ln) * 128 + kg * 8;
        size_t p1 = (size_t)(cbase + (w + 4) * 16 + ln) * 128 + kg * 8;
        BsC[0][0][w][l]     = *(const v8bf*)(W3h + p0);
        BsC[0][0][w + 4][l] = *(const v8bf*)(W3h + p1);
        BsC[0][1][w][l]     = *(const v8bf*)(W3l + p0);
        BsC[0][1][w + 4][l] = *(const v8bf*)(W3l + p1);
      }
      __syncthreads();

      v4f acc[8];
      v4f z4 = {0.f, 0.f, 0.f, 0.f};
#pragma unroll
      for (int i = 0; i < 8; ++i) acc[i] = z4;

#pragma unroll
      for (int kb = 0; kb < 4; ++kb) {
        int cur = kb & 1;
        v8bf r0, r1, r2, r3;
        if (kb < 3) {
          size_t p0 = (size_t)(cbase + w * 16 + ln) * 128 + (kb + 1) * 32 + kg * 8;
          size_t p1 = (size_t)(cbase + (w + 4) * 16 + ln) * 128 + (kb + 1) * 32 + kg * 8;
          r0 = *(const v8bf*)(W3h + p0);
          r1 = *(const v8bf*)(W3h + p1);
          r2 = *(const v8bf*)(W3l + p0);
          r3 = *(const v8bf*)(W3l + p1);
        }
#pragma unroll
        for (int nt = 0; nt < 8; ++nt) {
          v8bf bh = BsC[cur][0][nt][l];
          v8bf bl = BsC[cur][1][nt][l];
          acc[nt] = __builtin_amdgcn_mfma_f32_16x16x32_bf16(ayh[kb], bh, acc[nt], 0, 0, 0);
          acc[nt] = __builtin_amdgcn_mfma_f32_16x16x32_bf16(ayl[kb], bh, acc[nt], 0, 0, 0);
          acc[nt] = __builtin_amdgcn_mfma_f32_16x16x32_bf16(ayh[kb], bl, acc[nt], 0, 0, 0);
        }
        if (kb < 3) {
          int nxt = cur ^ 1;
          BsC[nxt][0][w][l]     = r0;
          BsC[nxt][0][w + 4][l] = r1;
          BsC[nxt][1][w][l]     = r2;
          BsC[nxt][1][w + 4][l] = r3;
        }
        __syncthreads();
      }

      int r0g = rbase + w * 16 + kg * 4;
#pragma unroll
      for (int nt = 0; nt < 8; ++nt) {
        float bv = bo3[cbase + nt * 16 + ln];
#pragma unroll
        for (int j = 0; j < 4; ++j) {
          out[(size_t)(r0g + j) * 256 + cbase + nt * 16 + ln] = acc[nt][j] + bv;
        }
      }
    }
  }
}

extern "C" void kernel_launch(void* const* d_in, const int* in_sizes, int n_in,
                              void* d_out, int out_size, void* d_ws, size_t ws_size,
                              hipStream_t stream) {
  const float* h        = (const float*)d_in[0];
  const float* h_full   = (const float*)d_in[1];
  const int*   z        = (const int*)d_in[2];
  const float* e_feat   = (const float*)d_in[4];
  const int*   abs_idx  = (const int*)d_in[5];
  const int*   att_dst  = (const int*)d_in[6];
  const float* att_dist = (const float*)d_in[7];
  const float* att_vec  = (const float*)d_in[8];
  const float* w_zemb   = (const float*)d_in[9];
  const float* w1_rad   = (const float*)d_in[10];
  const float* b1_rad   = (const float*)d_in[11];
  const float* w2_rad   = (const float*)d_in[12];
  const float* b2_rad   = (const float*)d_in[13];
  const float* wg1      = (const float*)d_in[14];
  const float* bg1      = (const float*)d_in[15];
  const float* wg2      = (const float*)d_in[16];
  const float* bg2      = (const float*)d_in[17];
  const float* we1      = (const float*)d_in[18];
  const float* be1      = (const float*)d_in[19];
  const float* we2      = (const float*)d_in[20];
  const float* be2      = (const float*)d_in[21];
  const float* wo1      = (const float*)d_in[22];
  const float* bo1      = (const float*)d_in[23];
  const float* wo2      = (const float*)d_in[24];
  const float* bo2      = (const float*)d_in[25];
  const float* wo3      = (const float*)d_in[26];
  const float* bo3      = (const float*)d_in[27];
  float* out = (float*)d_out;

  float* meta_f  = (float*)d_ws;                 // MAXACT*4
  float* vabs    = meta_f + MAXACT * 4;          // 64*80
  float* sfull   = vabs + NB * OD_;              // 512*80
  float* habs_g  = sfull + NE_ * OD_;            // 64*128
  __bf16* w2t_h  = (__bf16*)(habs_g + NB * 128); // 128*128 bf16
  __bf16* w2t_l  = w2t_h + 128 * 128;
  __bf16* w3t_h  = w2t_l + 128 * 128;            // 256*128 bf16
  __bf16* w3t_l  = w3t_h + 256 * 128;
  int* widx   = (int*)(w3t_l + 256 * 128);       // 8192
  int* active = widx + FLAT;                     // 4096
  int* meta_b = active + MAXACT;                 // 4096
  int* count  = meta_b + MAXACT;                 // 1 (+pad)
  float* big  = (float*)(count + 15);
  __bf16* ah_glob  = (__bf16*)big;               // MAXACT*128
  __bf16* al_glob  = ah_glob + MAXACT * 128;     // MAXACT*128
  float* coef_glob = (float*)(al_glob + MAXACT * 128);    // MAXACT*192
  __bf16* w2rt_h   = (__bf16*)(coef_glob + MAXACT * 192); // 4608*128
  __bf16* w2rt_l   = w2rt_h + 4608 * 128;
  float* part      = (float*)(w2rt_l + 4608 * 128);       // MAXACT*1088 (17.8 MB)

  k_prep<<<359, 256, 0, stream>>>(w2_rad, wo2, wo3, abs_idx, h, wg1,
                                  e_feat, we1, be1, we2, be2,
                                  w2rt_h, w2rt_l, w2t_h, w2t_l, w3t_h, w3t_l,
                                  habs_g, vabs, widx, count, sfull);
  k_scatter<<<16, 256, 0, stream>>>(att_dst, widx);
  k_build<<<32, 256, 0, stream>>>(widx, active, count);
  k_node4<<<1024, 128, 0, stream>>>(count, active, widx, att_dist, att_vec, z, w_zemb,
                                    abs_idx, w1_rad, b1_rad, h, habs_g, wg1, bg1, wg2, bg2,
                                    h_full, ah_glob, al_glob, coef_glob, meta_f, meta_b);
  k_mrgemm<<<dim3(36, 32), 256, 0, stream>>>(count, ah_glob, al_glob, w2rt_h, w2rt_l,
                                             b2_rad, coef_glob, part);
  k_combine<<<2048, 256, 0, stream>>>(count, part, meta_f, meta_b, vabs);
  k_head<<<512, 256, 0, stream>>>(vabs, sfull, wo1, bo1, w2t_h, w2t_l, bo2,
                                  w3t_h, w3t_l, bo3, out);
}